// Round 1
// baseline (1265.165 us; speedup 1.0000x reference)
//
#include <hip/hip_runtime.h>
#include <math.h>

#define DEV_INLINE __device__ __forceinline__

DEV_INLINE float wave_max_f(float v) {
#pragma unroll
  for (int o = 32; o > 0; o >>= 1) v = fmaxf(v, __shfl_xor(v, o, 64));
  return v;
}
DEV_INLINE float wave_sum_f(float v) {
#pragma unroll
  for (int o = 32; o > 0; o >>= 1) v += __shfl_xor(v, o, 64);
  return v;
}

DEV_INLINE int lower_bound_i(const int* __restrict__ a, int n, int key) {
  int lo = 0, hi = n;
  while (lo < hi) {
    int mid = (lo + hi) >> 1;
    if (a[mid] < key) lo = mid + 1; else hi = mid;
  }
  return lo;
}

// ---------------------------------------------------------------------------
// FP32 tiled GEMM: C[M,N] = A[M,K] @ B[K,N].  BM=BN=64, BK=16, 256 thr,
// 4x4 micro-tile per thread. K % 16 == 0 and N % 4 == 0 assumed (256/192/40).
// ---------------------------------------------------------------------------
__global__ __launch_bounds__(256) void gemm_tile(const float* __restrict__ A,
                                                 const float* __restrict__ B,
                                                 float* __restrict__ C,
                                                 int M, int N, int K) {
  __shared__ float As[16][68];  // [k][m], pad to 68 to break conflicts
  __shared__ float Bs[16][68];  // [k][n]
  const int tid = threadIdx.x;
  const int m0 = blockIdx.x * 64, n0 = blockIdx.y * 64;
  const int ty = tid >> 4, tx = tid & 15;
  const int arow = tid >> 2, acol4 = (tid & 3) << 2;   // A: 4 lanes per row (coalesced 64B)
  const int brow = tid >> 4, bcol4 = (tid & 15) << 2;  // B: 16 lanes per row (coalesced 256B)

  float acc[4][4];
#pragma unroll
  for (int i = 0; i < 4; ++i)
#pragma unroll
    for (int j = 0; j < 4; ++j) acc[i][j] = 0.f;

  const int gr_a = m0 + arow;
  const int gc_b = n0 + bcol4;

  for (int k0 = 0; k0 < K; k0 += 16) {
    float4 av = make_float4(0.f, 0.f, 0.f, 0.f);
    float4 bv = make_float4(0.f, 0.f, 0.f, 0.f);
    if (gr_a < M) av = *(const float4*)(A + (size_t)gr_a * K + k0 + acol4);
    if (gc_b < N) bv = *(const float4*)(B + (size_t)(k0 + brow) * N + gc_b);
    __syncthreads();  // prior iteration's LDS reads complete
    As[acol4 + 0][arow] = av.x;
    As[acol4 + 1][arow] = av.y;
    As[acol4 + 2][arow] = av.z;
    As[acol4 + 3][arow] = av.w;
    *(float4*)&Bs[brow][bcol4] = bv;  // 68-float row stride keeps 16B alignment
    __syncthreads();
#pragma unroll
    for (int kk = 0; kk < 16; ++kk) {
      float4 a = *(const float4*)&As[kk][ty << 2];
      float4 b = *(const float4*)&Bs[kk][tx << 2];
      float ar_[4] = {a.x, a.y, a.z, a.w};
      float br_[4] = {b.x, b.y, b.z, b.w};
#pragma unroll
      for (int i = 0; i < 4; ++i)
#pragma unroll
        for (int j = 0; j < 4; ++j) acc[i][j] = fmaf(ar_[i], br_[j], acc[i][j]);
    }
  }

  const int gc4 = n0 + (tx << 2);
#pragma unroll
  for (int i = 0; i < 4; ++i) {
    int gr = m0 + (ty << 2) + i;
    if (gr < M && gc4 < N) {
      float4 v = make_float4(acc[i][0], acc[i][1], acc[i][2], acc[i][3]);
      *(float4*)(C + (size_t)gr * N + gc4) = v;
    }
  }
}

// ---------------------------------------------------------------------------
// el[m,h] = sum_d h[m,h,d]*al[h,d];  er[m,h] likewise for m < n_dst.
// One block per row; wave w handles head w (block = H*64 threads).
// ---------------------------------------------------------------------------
template <int H, int D>
__global__ void elr_kernel(const float* __restrict__ h,
                           const float* __restrict__ al,
                           const float* __restrict__ ar,
                           float* __restrict__ el, float* __restrict__ er,
                           int M, int n_dst) {
  const int m = blockIdx.x;
  const int w = threadIdx.x >> 6, lane = threadIdx.x & 63;
  float hv = 0.f, av = 0.f, rv = 0.f;
  if (lane < D) {
    hv = h[(size_t)m * (H * D) + w * D + lane];
    av = al[w * D + lane];
    rv = ar[w * D + lane];
  }
  float se = wave_sum_f(hv * av);
  if (lane == 0) el[m * H + w] = se;
  if (m < n_dst) {
    float sr = wave_sum_f(hv * rv);
    if (lane == 0) er[m * H + w] = sr;
  }
}

// ---------------------------------------------------------------------------
// Per-destination-node softmax attention + aggregation. dst is SORTED, so
// each node owns a contiguous edge range (binary search). One wave per node,
// online softmax over chunks of 64 edges; lane k accumulates output dim k of
// every head. alpha broadcast via shuffles; h[src] reads are 64-lane coalesced.
// ---------------------------------------------------------------------------
template <int H, int D, bool RELU>
__global__ __launch_bounds__(256) void agg_kernel(
    const float* __restrict__ hsrc, const float* __restrict__ el,
    const float* __restrict__ er, const int* __restrict__ src,
    const int* __restrict__ dst, float* __restrict__ out,
    int n_edges, int n_dst) {
  constexpr int F = H * D;
  const int w = threadIdx.x >> 6, lane = threadIdx.x & 63;
  const int d = blockIdx.x * 4 + w;
  if (d >= n_dst) return;

  const int lo = lower_bound_i(dst, n_edges, d);
  const int hi = lower_bound_i(dst, n_edges, d + 1);
  if (hi <= lo) {  // no in-edges: segment_sum of nothing = 0
    if (lane < D) {
#pragma unroll
      for (int h = 0; h < H; ++h) out[(size_t)d * F + h * D + lane] = 0.f;
    }
    return;
  }

  float erv[H], m_run[H], s_run[H], acc[H];
#pragma unroll
  for (int h = 0; h < H; ++h) {
    erv[h] = er[d * H + h];
    m_run[h] = -INFINITY;
    s_run[h] = 0.f;
    acc[h] = 0.f;
  }

  for (int base = lo; base < hi; base += 64) {
    const int i = base + lane;
    const bool valid = i < hi;
    const int sid = valid ? src[i] : 0;
    float a[H];
#pragma unroll
    for (int h = 0; h < H; ++h) {
      float e;
      if (valid) {
        e = el[sid * H + h] + erv[h];
        e = e > 0.f ? e : 0.2f * e;  // leaky_relu 0.2
      } else {
        e = -INFINITY;
      }
      float cm = wave_max_f(e);
      float nm = fmaxf(m_run[h], cm);       // finite: chunk 0 has >=1 valid lane
      float r = __expf(m_run[h] - nm);      // exp(-inf)=0 on first chunk
      a[h] = valid ? __expf(e - nm) : 0.f;
      float ssum = wave_sum_f(a[h]);
      s_run[h] = s_run[h] * r + ssum;
      acc[h] *= r;
      m_run[h] = nm;
    }
    const int cnt = min(64, hi - base);
    for (int ei = 0; ei < cnt; ++ei) {
      const int sj = __shfl(sid, ei, 64);
      float aj[H];
#pragma unroll
      for (int h = 0; h < H; ++h) aj[h] = __shfl(a[h], ei, 64);
      if (lane < D) {
#pragma unroll
        for (int h = 0; h < H; ++h)
          acc[h] = fmaf(aj[h], hsrc[(size_t)sj * F + h * D + lane], acc[h]);
      }
    }
  }

  if (lane < D) {
#pragma unroll
    for (int h = 0; h < H; ++h) {
      float v = acc[h] / s_run[h];
      if (RELU) v = fmaxf(v, 0.f);
      out[(size_t)d * F + h * D + lane] = v;
    }
  }
}

// ---------------------------------------------------------------------------
extern "C" void kernel_launch(void* const* d_in, const int* in_sizes, int n_in,
                              void* d_out, int out_size, void* d_ws, size_t ws_size,
                              hipStream_t stream) {
  const float* x   = (const float*)d_in[0];
  const int* src0  = (const int*)d_in[1];
  const int* dst0  = (const int*)d_in[2];
  const int* src1  = (const int*)d_in[3];
  const int* dst1  = (const int*)d_in[4];
  const int* src2  = (const int*)d_in[5];
  const int* dst2  = (const int*)d_in[6];
  const float* W0  = (const float*)d_in[7];
  const float* al0 = (const float*)d_in[8];
  const float* ar0 = (const float*)d_in[9];
  const float* W1  = (const float*)d_in[10];
  const float* al1 = (const float*)d_in[11];
  const float* ar1 = (const float*)d_in[12];
  const float* W2  = (const float*)d_in[13];
  const float* al2 = (const float*)d_in[14];
  const float* ar2 = (const float*)d_in[15];

  const int N0 = 200000, N1 = 100000, N2 = 50000, N3 = 25000;
  const int E0 = in_sizes[1], E1 = in_sizes[3], E2 = in_sizes[5];
  const int Fin = 256, F = 192, C = 40;

  // workspace layout (floats): h_buf reused for h0/h1/h2; o_buf for out0/out1
  float* ws     = (float*)d_ws;
  float* h_buf  = ws;                        // up to 200000*192 = 38.4M floats
  float* o_buf  = h_buf + (size_t)N0 * F;    // up to 100000*192 = 19.2M floats
  float* el_buf = o_buf + (size_t)N1 * F;    // up to 200000*3
  float* er_buf = el_buf + (size_t)N0 * 3;   // up to 100000*3

  dim3 blk(256);

  // ---- Layer 0: x(200000x256) @ W0(256x192) ----
  gemm_tile<<<dim3((N0 + 63) / 64, F / 64), blk, 0, stream>>>(x, W0, h_buf, N0, F, Fin);
  elr_kernel<3, 64><<<dim3(N0), dim3(192), 0, stream>>>(h_buf, al0, ar0, el_buf, er_buf, N0, N1);
  agg_kernel<3, 64, true><<<dim3((N1 + 3) / 4), blk, 0, stream>>>(
      h_buf, el_buf, er_buf, src0, dst0, o_buf, E0, N1);

  // ---- Layer 1: out0(100000x192) @ W1(192x192) ----
  gemm_tile<<<dim3((N1 + 63) / 64, F / 64), blk, 0, stream>>>(o_buf, W1, h_buf, N1, F, F);
  elr_kernel<3, 64><<<dim3(N1), dim3(192), 0, stream>>>(h_buf, al1, ar1, el_buf, er_buf, N1, N2);
  agg_kernel<3, 64, true><<<dim3((N2 + 3) / 4), blk, 0, stream>>>(
      h_buf, el_buf, er_buf, src1, dst1, o_buf, E1, N2);

  // ---- Layer 2: out1(50000x192) @ W2(192x40), H=1, C=40, no relu ----
  gemm_tile<<<dim3((N2 + 63) / 64, (C + 63) / 64), blk, 0, stream>>>(o_buf, W2, h_buf, N2, C, F);
  elr_kernel<1, 40><<<dim3(N2), dim3(64), 0, stream>>>(h_buf, al2, ar2, el_buf, er_buf, N2, N3);
  agg_kernel<1, 40, false><<<dim3((N3 + 3) / 4), blk, 0, stream>>>(
      h_buf, el_buf, er_buf, src2, dst2, (float*)d_out, E2, N3);
}

// Round 2
// 773.045 us; speedup vs baseline: 1.6366x; 1.6366x over previous
//
#include <hip/hip_runtime.h>
#include <math.h>

#define DEV_INLINE __device__ __forceinline__

typedef __attribute__((ext_vector_type(8))) short short8v;
typedef __attribute__((ext_vector_type(4))) short short4v;
typedef __attribute__((ext_vector_type(4))) float float4v;

DEV_INLINE float wave_max_f(float v) {
#pragma unroll
  for (int o = 32; o > 0; o >>= 1) v = fmaxf(v, __shfl_xor(v, o, 64));
  return v;
}
DEV_INLINE float wave_sum_f(float v) {
#pragma unroll
  for (int o = 32; o > 0; o >>= 1) v += __shfl_xor(v, o, 64);
  return v;
}

// fp32 -> bf16 round-to-nearest-even (no NaN handling needed: data is finite)
DEV_INLINE unsigned short f2bf_rtn(float f) {
  unsigned u = __float_as_uint(f);
  u += 0x7FFFu + ((u >> 16) & 1u);
  return (unsigned short)(u >> 16);
}
DEV_INLINE float bf2f(unsigned short s) { return __uint_as_float(((unsigned)s) << 16); }

// ---------------------------------------------------------------------------
// Weight pre-pass: Wt_hi[n][k], Wt_lo[n][k] (transposed, split into bf16 hi/lo)
// ---------------------------------------------------------------------------
__global__ void conv_w(const float* __restrict__ W, short* __restrict__ Wh,
                       short* __restrict__ Wl, int K, int N) {
  int idx = blockIdx.x * 256 + threadIdx.x;
  if (idx >= K * N) return;
  int n = idx / K, k = idx - n * K;
  float w = W[(size_t)k * N + n];
  unsigned short h = f2bf_rtn(w);
  Wh[idx] = (short)h;
  Wl[idx] = (short)f2bf_rtn(w - bf2f(h));
}

// ---------------------------------------------------------------------------
// CSR offsets from sorted dst: off[d] = first edge index with dst >= d,
// off[n_dst] = E.
// ---------------------------------------------------------------------------
__global__ void csr_build(const int* __restrict__ dst, int* __restrict__ off,
                          int E, int n_dst) {
  int i = blockIdx.x * 256 + threadIdx.x;
  if (i >= E) return;
  int d = dst[i];
  int p = (i == 0) ? -1 : dst[i - 1];
  for (int q = p + 1; q <= d; ++q) off[q] = i;
  if (i == E - 1)
    for (int q = d + 1; q <= n_dst; ++q) off[q] = E;
}

// ---------------------------------------------------------------------------
// MFMA GEMM, fp32-accurate via bf16 hi/lo split (3 MFMAs: hh + hl + lh).
// C[M,N] = A[M,K] @ B[K,N].  A fp32 in global (converted while staging);
// B pre-split/transposed: Bt[n][k] bf16 planes.  BM=128, BN=64, BK=32,
// 256 threads = 4 waves, wave w computes rows w*32..w*32+31 x 64 cols
// as 2x4 tiles of v_mfma_f32_16x16x32_bf16.
// A-frag: lane holds A[m=lane&15][k=quad*8+j]; B-frag: B[k=quad*8+j][n=lane&15];
// C/D: col=lane&15, row=quad*4+reg  (m89/m91-verified layouts).
// ---------------------------------------------------------------------------
__global__ __launch_bounds__(256) void gemm_mfma(
    const float* __restrict__ A, const short* __restrict__ Bth,
    const short* __restrict__ Btl, float* __restrict__ C,
    int M, int N, int K) {
  __shared__ short As_h[128][40];  // stride 40 shorts (80B): 2-way-free frag reads
  __shared__ short As_l[128][40];
  __shared__ short Bs_h[64][40];
  __shared__ short Bs_l[64][40];
  const int tid = threadIdx.x;
  const int w = tid >> 6, lane = tid & 63;
  const int quad = lane >> 4, l16 = lane & 15;
  const int m0 = blockIdx.x * 128, n0 = blockIdx.y * 64;

  float4v acc[2][4];
#pragma unroll
  for (int mt = 0; mt < 2; ++mt)
#pragma unroll
    for (int nt = 0; nt < 4; ++nt)
#pragma unroll
      for (int r = 0; r < 4; ++r) acc[mt][nt][r] = 0.f;

  const int ar = tid >> 3;          // 0..31 (A stage row base)
  const int ac4 = (tid & 7) * 4;    // 0..28 (A stage k quad)
  const int bn = tid >> 2;          // 0..63 (B stage row)
  const int bk8 = (tid & 3) * 8;    // 0..24 (B stage k oct)

  for (int k0 = 0; k0 < K; k0 += 32) {
    // -- load to regs (before barrier) --
    float4 a_reg[4];
#pragma unroll
    for (int p = 0; p < 4; ++p) {
      int gr = m0 + ar + p * 32;
      a_reg[p] = (gr < M) ? *(const float4*)(A + (size_t)gr * K + k0 + ac4)
                          : make_float4(0.f, 0.f, 0.f, 0.f);
    }
    short8v b_h, b_l;
    {
      int gn = n0 + bn;
      if (gn < N) {
        b_h = *(const short8v*)(Bth + (size_t)gn * K + k0 + bk8);
        b_l = *(const short8v*)(Btl + (size_t)gn * K + k0 + bk8);
      } else {
#pragma unroll
        for (int j = 0; j < 8; ++j) { b_h[j] = 0; b_l[j] = 0; }
      }
    }
    __syncthreads();  // previous iteration's frag reads done
    // -- stage to LDS (A: split fp32 -> bf16 hi/lo) --
#pragma unroll
    for (int p = 0; p < 4; ++p) {
      int r = ar + p * 32;
      float vs[4] = {a_reg[p].x, a_reg[p].y, a_reg[p].z, a_reg[p].w};
      short4v hv, lv;
#pragma unroll
      for (int j = 0; j < 4; ++j) {
        unsigned short h = f2bf_rtn(vs[j]);
        hv[j] = (short)h;
        lv[j] = (short)f2bf_rtn(vs[j] - bf2f(h));
      }
      *(short4v*)&As_h[r][ac4] = hv;
      *(short4v*)&As_l[r][ac4] = lv;
    }
    *(short8v*)&Bs_h[bn][bk8] = b_h;
    *(short8v*)&Bs_l[bn][bk8] = b_l;
    __syncthreads();
    // -- fragments --
    short8v afh[2], afl[2], bfh[4], bfl[4];
#pragma unroll
    for (int mt = 0; mt < 2; ++mt) {
      int row = w * 32 + mt * 16 + l16;
      afh[mt] = *(const short8v*)&As_h[row][quad * 8];
      afl[mt] = *(const short8v*)&As_l[row][quad * 8];
    }
#pragma unroll
    for (int nt = 0; nt < 4; ++nt) {
      int col = nt * 16 + l16;
      bfh[nt] = *(const short8v*)&Bs_h[col][quad * 8];
      bfl[nt] = *(const short8v*)&Bs_l[col][quad * 8];
    }
    // -- 3-term MFMA: Ahi*Bhi + Ahi*Blo + Alo*Bhi --
#pragma unroll
    for (int mt = 0; mt < 2; ++mt)
#pragma unroll
      for (int nt = 0; nt < 4; ++nt) {
        acc[mt][nt] = __builtin_amdgcn_mfma_f32_16x16x32_bf16(afh[mt], bfh[nt], acc[mt][nt], 0, 0, 0);
        acc[mt][nt] = __builtin_amdgcn_mfma_f32_16x16x32_bf16(afh[mt], bfl[nt], acc[mt][nt], 0, 0, 0);
        acc[mt][nt] = __builtin_amdgcn_mfma_f32_16x16x32_bf16(afl[mt], bfh[nt], acc[mt][nt], 0, 0, 0);
      }
  }
  // -- epilogue --
#pragma unroll
  for (int mt = 0; mt < 2; ++mt)
#pragma unroll
    for (int r = 0; r < 4; ++r) {
      int gr = m0 + w * 32 + mt * 16 + quad * 4 + r;
      if (gr < M) {
#pragma unroll
        for (int nt = 0; nt < 4; ++nt) {
          int gc = n0 + nt * 16 + l16;
          if (gc < N) C[(size_t)gr * N + gc] = acc[mt][nt][r];
        }
      }
    }
}

// ---------------------------------------------------------------------------
// el[m,h] = sum_d h[m,h,d]*al[h,d];  er likewise for m < n_dst.
// One wave per row, float4 loads, 16-lane group reduction per head.
// ---------------------------------------------------------------------------
template <int H, int D>
__global__ __launch_bounds__(256) void elr_kernel(
    const float* __restrict__ h, const float* __restrict__ al,
    const float* __restrict__ ar, float* __restrict__ el,
    float* __restrict__ er, int M, int n_dst) {
  constexpr int F = H * D;
  constexpr int LANES = F / 4;
  const int w = threadIdx.x >> 6, lane = threadIdx.x & 63;
  const int m = blockIdx.x * 4 + w;
  if (m >= M) return;
  const int f4 = lane * 4;
  float4 hv = make_float4(0.f, 0.f, 0.f, 0.f);
  float4 av = hv, rv = hv;
  if (lane < LANES) {
    hv = *(const float4*)(h + (size_t)m * F + f4);
    av = *(const float4*)(al + f4);
    rv = *(const float4*)(ar + f4);
  }
  float pl = hv.x * av.x + hv.y * av.y + hv.z * av.z + hv.w * av.w;
  float pr = hv.x * rv.x + hv.y * rv.y + hv.z * rv.z + hv.w * rv.w;
#pragma unroll
  for (int o = 8; o >= 1; o >>= 1) {
    pl += __shfl_xor(pl, o, 16);
    pr += __shfl_xor(pr, o, 16);
  }
  if ((lane & 15) == 0 && f4 < F) {
    int hh = f4 / D;
    el[m * H + hh] = pl;
    if (m < n_dst) er[m * H + hh] = pr;
  }
}

// ---------------------------------------------------------------------------
// Softmax attention + aggregation. One wave per dst node, contiguous edge
// range from CSR offsets; online softmax per head over 64-edge chunks.
// Accumulate phase: lane owns 4 consecutive features (float4 gather).
// ---------------------------------------------------------------------------
template <int H, int D, bool RELU>
__global__ __launch_bounds__(256) void agg_kernel(
    const float* __restrict__ hsrc, const float* __restrict__ el,
    const float* __restrict__ er, const int* __restrict__ src,
    const int* __restrict__ off, float* __restrict__ out, int n_dst) {
  constexpr int F = H * D;
  constexpr int QL = F / 4;  // active lanes in accumulate phase
  const int w = threadIdx.x >> 6, lane = threadIdx.x & 63;
  const int d = blockIdx.x * 4 + w;
  if (d >= n_dst) return;
  const int lo = off[d], hi = off[d + 1];
  const int f4 = lane * 4;
  const bool factive = lane < QL;
  const int hh = f4 / D;  // this lane's head in accumulate phase

  if (hi <= lo) {
    if (factive) *(float4*)(out + (size_t)d * F + f4) = make_float4(0.f, 0.f, 0.f, 0.f);
    return;
  }

  float erv[H], m_run[H], s_run[H];
  float4 acc = make_float4(0.f, 0.f, 0.f, 0.f);
#pragma unroll
  for (int h = 0; h < H; ++h) {
    erv[h] = er[d * H + h];
    m_run[h] = -INFINITY;
    s_run[h] = 0.f;
  }

  for (int base = lo; base < hi; base += 64) {
    const int i = base + lane;
    const bool valid = i < hi;
    const int sid = valid ? src[i] : 0;
    float a[H], rsel = 1.f;
#pragma unroll
    for (int h = 0; h < H; ++h) {
      float e = -INFINITY;
      if (valid) {
        e = el[sid * H + h] + erv[h];
        e = e > 0.f ? e : 0.2f * e;  // leaky_relu 0.2
      }
      float nm = fmaxf(m_run[h], wave_max_f(e));
      float r = __expf(m_run[h] - nm);  // exp(-inf)=0 on first chunk
      a[h] = valid ? __expf(e - nm) : 0.f;
      s_run[h] = s_run[h] * r + wave_sum_f(a[h]);
      m_run[h] = nm;
      if (h == hh) rsel = r;
    }
    acc.x *= rsel; acc.y *= rsel; acc.z *= rsel; acc.w *= rsel;

    const int cnt = min(64, hi - base);
    for (int ei = 0; ei < cnt; ++ei) {
      const int sj = __shfl(sid, ei, 64);
      float aj[H];
#pragma unroll
      for (int h = 0; h < H; ++h) aj[h] = __shfl(a[h], ei, 64);
      float as = aj[0];
#pragma unroll
      for (int h = 1; h < H; ++h)
        if (hh == h) as = aj[h];
      if (factive) {
        const float4 hv = *(const float4*)(hsrc + (size_t)sj * F + f4);
        acc.x = fmaf(as, hv.x, acc.x);
        acc.y = fmaf(as, hv.y, acc.y);
        acc.z = fmaf(as, hv.z, acc.z);
        acc.w = fmaf(as, hv.w, acc.w);
      }
    }
  }

  float s = s_run[0];
#pragma unroll
  for (int h = 1; h < H; ++h)
    if (hh == h) s = s_run[h];
  if (factive) {
    float4 o;
    o.x = acc.x / s; o.y = acc.y / s; o.z = acc.z / s; o.w = acc.w / s;
    if (RELU) {
      o.x = fmaxf(o.x, 0.f); o.y = fmaxf(o.y, 0.f);
      o.z = fmaxf(o.z, 0.f); o.w = fmaxf(o.w, 0.f);
    }
    *(float4*)(out + (size_t)d * F + f4) = o;
  }
}

// ---------------------------------------------------------------------------
extern "C" void kernel_launch(void* const* d_in, const int* in_sizes, int n_in,
                              void* d_out, int out_size, void* d_ws, size_t ws_size,
                              hipStream_t stream) {
  const float* x   = (const float*)d_in[0];
  const int* src0  = (const int*)d_in[1];
  const int* dst0  = (const int*)d_in[2];
  const int* src1  = (const int*)d_in[3];
  const int* dst1  = (const int*)d_in[4];
  const int* src2  = (const int*)d_in[5];
  const int* dst2  = (const int*)d_in[6];
  const float* W0  = (const float*)d_in[7];
  const float* al0 = (const float*)d_in[8];
  const float* ar0 = (const float*)d_in[9];
  const float* W1  = (const float*)d_in[10];
  const float* al1 = (const float*)d_in[11];
  const float* ar1 = (const float*)d_in[12];
  const float* W2  = (const float*)d_in[13];
  const float* al2 = (const float*)d_in[14];
  const float* ar2 = (const float*)d_in[15];

  const int N0 = 200000, N1 = 100000, N2 = 50000, N3 = 25000;
  const int E0 = in_sizes[1], E1 = in_sizes[3], E2 = in_sizes[5];
  const int Fin = 256, F = 192, C = 40;

  // ---- workspace layout ----
  float* ws     = (float*)d_ws;
  float* h_buf  = ws;                         // 200000*192 floats
  float* o_buf  = h_buf + (size_t)N0 * F;     // 100000*192 floats
  float* el_buf = o_buf + (size_t)N1 * F;     // 200000*3
  float* er_buf = el_buf + (size_t)N0 * 3;    // 100000*3
  short* w0h    = (short*)(er_buf + (size_t)N1 * 3);
  short* w0l    = w0h + 192 * 256;
  short* w1h    = w0l + 192 * 256;
  short* w1l    = w1h + 192 * 192;
  short* w2h    = w1l + 192 * 192;
  short* w2l    = w2h + 40 * 192;
  int*   off0   = (int*)(w2l + 40 * 192);
  int*   off1   = off0 + (N1 + 1);
  int*   off2   = off1 + (N2 + 1);

  dim3 blk(256);

  // ---- pre-passes: weight split/transpose + CSR offsets ----
  conv_w<<<dim3((256 * 192 + 255) / 256), blk, 0, stream>>>(W0, w0h, w0l, Fin, F);
  conv_w<<<dim3((192 * 192 + 255) / 256), blk, 0, stream>>>(W1, w1h, w1l, F, F);
  conv_w<<<dim3((192 * 40 + 255) / 256), blk, 0, stream>>>(W2, w2h, w2l, F, C);
  csr_build<<<dim3((E0 + 255) / 256), blk, 0, stream>>>(dst0, off0, E0, N1);
  csr_build<<<dim3((E1 + 255) / 256), blk, 0, stream>>>(dst1, off1, E1, N2);
  csr_build<<<dim3((E2 + 255) / 256), blk, 0, stream>>>(dst2, off2, E2, N3);

  // ---- Layer 0 ----
  gemm_mfma<<<dim3((N0 + 127) / 128, F / 64), blk, 0, stream>>>(x, w0h, w0l, h_buf, N0, F, Fin);
  elr_kernel<3, 64><<<dim3((N0 + 3) / 4), blk, 0, stream>>>(h_buf, al0, ar0, el_buf, er_buf, N0, N1);
  agg_kernel<3, 64, true><<<dim3((N1 + 3) / 4), blk, 0, stream>>>(
      h_buf, el_buf, er_buf, src0, off0, o_buf, N1);

  // ---- Layer 1 ----
  gemm_mfma<<<dim3((N1 + 127) / 128, F / 64), blk, 0, stream>>>(o_buf, w1h, w1l, h_buf, N1, F, F);
  elr_kernel<3, 64><<<dim3((N1 + 3) / 4), blk, 0, stream>>>(h_buf, al1, ar1, el_buf, er_buf, N1, N2);
  agg_kernel<3, 64, true><<<dim3((N2 + 3) / 4), blk, 0, stream>>>(
      h_buf, el_buf, er_buf, src1, off1, o_buf, N2);

  // ---- Layer 2 (H=1, C=40, no relu) ----
  gemm_mfma<<<dim3((N2 + 127) / 128, 1), blk, 0, stream>>>(o_buf, w2h, w2l, h_buf, N2, C, F);
  elr_kernel<1, 40><<<dim3((N2 + 3) / 4), blk, 0, stream>>>(h_buf, al2, ar2, el_buf, er_buf, N2, N3);
  agg_kernel<1, 40, false><<<dim3((N3 + 3) / 4), blk, 0, stream>>>(
      h_buf, el_buf, er_buf, src2, off2, (float*)d_out, N3);
}

// Round 3
// 643.587 us; speedup vs baseline: 1.9658x; 1.2012x over previous
//
#include <hip/hip_runtime.h>
#include <math.h>

#define DEV_INLINE __device__ __forceinline__

typedef __attribute__((ext_vector_type(8))) short short8v;
typedef __attribute__((ext_vector_type(4))) float float4v;

// fp32 -> bf16 round-to-nearest-even (finite data only)
DEV_INLINE unsigned short f2bf_rtn(float f) {
  unsigned u = __float_as_uint(f);
  u += 0x7FFFu + ((u >> 16) & 1u);
  return (unsigned short)(u >> 16);
}
DEV_INLINE float bf2f(unsigned short s) { return __uint_as_float(((unsigned)s) << 16); }

// LDS swizzle: row-major [row][32 shorts], k-oct (16B unit) XORed with row&3.
// Guarantees 16B-aligned b128 ops and conflict-free frag reads/stage writes.
DEV_INLINE int soff(int row, int oct) { return row * 32 + ((oct ^ (row & 3)) << 3); }

// ---------------------------------------------------------------------------
// Pre-pass: all three weight matrices -> transposed bf16 hi/lo planes.
// ---------------------------------------------------------------------------
__global__ void conv_w_all(const float* __restrict__ W0, const float* __restrict__ W1,
                           const float* __restrict__ W2, short* __restrict__ w0h,
                           short* __restrict__ w0l, short* __restrict__ w1h,
                           short* __restrict__ w1l, short* __restrict__ w2h,
                           short* __restrict__ w2l) {
  const int S0 = 256 * 192, S1 = 192 * 192, S2 = 192 * 40;
  int idx = blockIdx.x * 256 + threadIdx.x;
  const float* W; short *Wh, *Wl; int K;
  if (idx < S0) { W = W0; Wh = w0h; Wl = w0l; K = 256; }
  else if (idx < S0 + S1) { idx -= S0; W = W1; Wh = w1h; Wl = w1l; K = 192; }
  else if (idx < S0 + S1 + S2) { idx -= S0 + S1; W = W2; Wh = w2h; Wl = w2l; K = 192; }
  else return;
  int n = idx / K, k = idx - n * K;
  int N = (W == W0 || W == W1) ? 192 : 40;
  float w = W[(size_t)k * N + n];
  unsigned short h = f2bf_rtn(w);
  Wh[idx] = (short)h;
  Wl[idx] = (short)f2bf_rtn(w - bf2f(h));
}

// ---------------------------------------------------------------------------
// Pre-pass: CSR offsets from all three sorted dst arrays.
// ---------------------------------------------------------------------------
__global__ void csr_all(const int* __restrict__ d0, const int* __restrict__ d1,
                        const int* __restrict__ d2, int* __restrict__ o0,
                        int* __restrict__ o1, int* __restrict__ o2,
                        int E0, int E1, int E2, int n1, int n2, int n3) {
  int i = blockIdx.x * 256 + threadIdx.x;
  const int* dst; int* off; int E, nd;
  if (i < E0) { dst = d0; off = o0; E = E0; nd = n1; }
  else if (i < E0 + E1) { i -= E0; dst = d1; off = o1; E = E1; nd = n2; }
  else if (i < E0 + E1 + E2) { i -= E0 + E1; dst = d2; off = o2; E = E2; nd = n3; }
  else return;
  int d = dst[i];
  int p = (i == 0) ? -1 : dst[i - 1];
  for (int q = p + 1; q <= d; ++q) off[q] = i;
  if (i == E - 1)
    for (int q = d + 1; q <= nd; ++q) off[q] = E;
}

// ---------------------------------------------------------------------------
// Full-width MFMA GEMM (bf16 3-term hi/lo split, fp32-accurate) with fused
// el/er epilogue.  BM=128, BN=NT*16 (full output width), BK=32, 256 threads.
// Wave w owns rows w*32..w*32+31 across ALL NT column tiles -> A read ONCE,
// complete rows in-register for the el/er per-head reductions.
// LDS XOR-swizzled (see soff).  A converted fp32->hi/lo inline (once now).
// ---------------------------------------------------------------------------
template <int NT, int H>
__global__ __launch_bounds__(256) void gemm_fused(
    const float* __restrict__ A, const short* __restrict__ Bth,
    const short* __restrict__ Btl, const float* __restrict__ al,
    const float* __restrict__ ar, float* __restrict__ C,
    float* __restrict__ el, float* __restrict__ er,
    int M, int N, int K, int n_dst) {
  constexpr int BN = NT * 16;
  constexpr int BREP = (BN + 63) / 64;
  constexpr int TPH = NT / H;  // column tiles per head
  __shared__ short As_h[128 * 32], As_l[128 * 32];
  __shared__ short Bs_h[BN * 32], Bs_l[BN * 32];
  const int tid = threadIdx.x;
  const int w = tid >> 6, lane = tid & 63;
  const int quad = lane >> 4, l16 = lane & 15;
  const int m0 = blockIdx.x * 128;

  float4v acc[2][NT];
#pragma unroll
  for (int mt = 0; mt < 2; ++mt)
#pragma unroll
    for (int nt = 0; nt < NT; ++nt)
#pragma unroll
      for (int r = 0; r < 4; ++r) acc[mt][nt][r] = 0.f;

  const int sr = tid >> 2;        // stage row 0..63
  const int oct = tid & 3;        // k-oct 0..3

  for (int k0 = 0; k0 < K; k0 += 32) {
    // ---- global loads (before barrier) ----
    float4 a0[2], a1[2];
#pragma unroll
    for (int p = 0; p < 2; ++p) {
      int gr = m0 + sr + p * 64;
      if (gr < M) {
        const float* ap = A + (size_t)gr * K + k0 + oct * 8;
        a0[p] = *(const float4*)ap;
        a1[p] = *(const float4*)(ap + 4);
      } else {
        a0[p] = make_float4(0.f, 0.f, 0.f, 0.f);
        a1[p] = a0[p];
      }
    }
    short8v bh[BREP], bl[BREP];
#pragma unroll
    for (int q = 0; q < BREP; ++q) {
      int n = sr + q * 64;
      if (n < BN) {
        if (n < N) {
          bh[q] = *(const short8v*)(Bth + (size_t)n * K + k0 + oct * 8);
          bl[q] = *(const short8v*)(Btl + (size_t)n * K + k0 + oct * 8);
        } else {
#pragma unroll
          for (int j = 0; j < 8; ++j) { bh[q][j] = 0; bl[q][j] = 0; }
        }
      }
    }
    __syncthreads();  // prior iteration's frag reads done
    // ---- stage ----
#pragma unroll
    for (int p = 0; p < 2; ++p) {
      int r = sr + p * 64;
      float vs[8] = {a0[p].x, a0[p].y, a0[p].z, a0[p].w,
                     a1[p].x, a1[p].y, a1[p].z, a1[p].w};
      short8v hv, lv;
#pragma unroll
      for (int j = 0; j < 8; ++j) {
        unsigned short h = f2bf_rtn(vs[j]);
        hv[j] = (short)h;
        lv[j] = (short)f2bf_rtn(vs[j] - bf2f(h));
      }
      *(short8v*)(As_h + soff(r, oct)) = hv;
      *(short8v*)(As_l + soff(r, oct)) = lv;
    }
#pragma unroll
    for (int q = 0; q < BREP; ++q) {
      int n = sr + q * 64;
      if (n < BN) {
        *(short8v*)(Bs_h + soff(n, oct)) = bh[q];
        *(short8v*)(Bs_l + soff(n, oct)) = bl[q];
      }
    }
    __syncthreads();
    // ---- fragments + MFMA ----
    short8v afh[2], afl[2];
#pragma unroll
    for (int mt = 0; mt < 2; ++mt) {
      int row = w * 32 + mt * 16 + l16;
      afh[mt] = *(const short8v*)(As_h + soff(row, quad));
      afl[mt] = *(const short8v*)(As_l + soff(row, quad));
    }
#pragma unroll
    for (int nt = 0; nt < NT; ++nt) {
      int col = nt * 16 + l16;
      short8v bfh = *(const short8v*)(Bs_h + soff(col, quad));
      short8v bfl = *(const short8v*)(Bs_l + soff(col, quad));
#pragma unroll
      for (int mt = 0; mt < 2; ++mt) {
        acc[mt][nt] = __builtin_amdgcn_mfma_f32_16x16x32_bf16(afh[mt], bfh, acc[mt][nt], 0, 0, 0);
        acc[mt][nt] = __builtin_amdgcn_mfma_f32_16x16x32_bf16(afh[mt], bfl, acc[mt][nt], 0, 0, 0);
        acc[mt][nt] = __builtin_amdgcn_mfma_f32_16x16x32_bf16(afl[mt], bfh, acc[mt][nt], 0, 0, 0);
      }
    }
  }

  // ---- epilogue: C store + fused el/er ----
  float av[NT], rv[NT];
#pragma unroll
  for (int nt = 0; nt < NT; ++nt) {
    int col = nt * 16 + l16;
    av[nt] = (col < N) ? al[col] : 0.f;
    rv[nt] = (col < N) ? ar[col] : 0.f;
  }
#pragma unroll
  for (int mt = 0; mt < 2; ++mt)
#pragma unroll
    for (int r = 0; r < 4; ++r) {
      int gm = m0 + w * 32 + mt * 16 + quad * 4 + r;
      if (gm >= M) continue;
      float pl[H], pr[H];
#pragma unroll
      for (int h = 0; h < H; ++h) { pl[h] = 0.f; pr[h] = 0.f; }
#pragma unroll
      for (int nt = 0; nt < NT; ++nt) {
        int h = nt / TPH;
        pl[h] = fmaf(acc[mt][nt][r], av[nt], pl[h]);
        pr[h] = fmaf(acc[mt][nt][r], rv[nt], pr[h]);
      }
#pragma unroll
      for (int h = 0; h < H; ++h) {
#pragma unroll
        for (int o = 8; o >= 1; o >>= 1) {
          pl[h] += __shfl_xor(pl[h], o, 16);
          pr[h] += __shfl_xor(pr[h], o, 16);
        }
      }
      if (l16 == 0) {
#pragma unroll
        for (int h = 0; h < H; ++h) {
          el[gm * H + h] = pl[h];
          if (gm < n_dst) er[gm * H + h] = pr[h];
        }
      }
#pragma unroll
      for (int nt = 0; nt < NT; ++nt) {
        int col = nt * 16 + l16;
        if (col < N) C[(size_t)gm * N + col] = acc[mt][nt][r];
      }
    }
}

// ---------------------------------------------------------------------------
// Aggregation v2: 16-lane group per dst node (16 nodes/block), CSR ranges.
// Max-free softmax (|e| small -> exp safe; alpha mathematically identical).
// Per 16-edge chunk: phase 1 computes w=exp(lrelu(el+er)) edge-parallel into
// LDS; phase 2 gathers h rows with all lanes active + 1-deep prefetch.
// ---------------------------------------------------------------------------
template <int H, int D, bool RELU>
__global__ __launch_bounds__(256) void agg2_kernel(
    const float* __restrict__ hsrc, const float* __restrict__ el,
    const float* __restrict__ er, const int* __restrict__ src,
    const int* __restrict__ off, float* __restrict__ out, int n_dst) {
  constexpr int F = H * D;
  constexpr int NP = (F + 63) / 64;  // float4 passes per lane
  __shared__ float wbuf[16][16][H];
  __shared__ int sbuf[16][16];
  const int g = threadIdx.x >> 4, l = threadIdx.x & 15;
  const int d = blockIdx.x * 16 + g;
  if (d >= n_dst) return;
  const int lo = off[d], hi = off[d + 1];

  if (hi <= lo) {
#pragma unroll
    for (int p = 0; p < NP; ++p) {
      int c4 = (p * 16 + l) * 4;
      if (c4 < F) *(float4*)(out + (size_t)d * F + c4) = make_float4(0.f, 0.f, 0.f, 0.f);
    }
    return;
  }

  float erv[H], s_part[H];
#pragma unroll
  for (int h = 0; h < H; ++h) {
    erv[h] = er[d * H + h];
    s_part[h] = 0.f;
  }
  float4 acc[NP];
#pragma unroll
  for (int p = 0; p < NP; ++p) acc[p] = make_float4(0.f, 0.f, 0.f, 0.f);

  for (int base = lo; base < hi; base += 16) {
    const int i = base + l;
    const bool valid = i < hi;
    const int sid = valid ? src[i] : 0;
#pragma unroll
    for (int h = 0; h < H; ++h) {
      float e = 0.f;
      if (valid) {
        e = el[sid * H + h] + erv[h];
        e = e > 0.f ? e : 0.2f * e;  // leaky_relu 0.2
        e = __expf(e);
      }
      s_part[h] += e;
      wbuf[g][l][h] = e;
    }
    sbuf[g][l] = sid;  // same wave: no barrier needed

    const int cnt = min(16, hi - base);
    // prefetch edge 0
    int sj = sbuf[g][0];
    float4 hv[NP], hn[NP];
#pragma unroll
    for (int p = 0; p < NP; ++p) {
      int c4 = (p * 16 + l) * 4;
      hv[p] = (c4 < F) ? *(const float4*)(hsrc + (size_t)sj * F + c4)
                       : make_float4(0.f, 0.f, 0.f, 0.f);
    }
    for (int ei = 0; ei < cnt; ++ei) {
      if (ei + 1 < cnt) {
        int sj2 = sbuf[g][ei + 1];
#pragma unroll
        for (int p = 0; p < NP; ++p) {
          int c4 = (p * 16 + l) * 4;
          hn[p] = (c4 < F) ? *(const float4*)(hsrc + (size_t)sj2 * F + c4)
                           : make_float4(0.f, 0.f, 0.f, 0.f);
        }
      }
#pragma unroll
      for (int p = 0; p < NP; ++p) {
        int c4 = (p * 16 + l) * 4;
        float wc = wbuf[g][ei][c4 / D];
        acc[p].x = fmaf(wc, hv[p].x, acc[p].x);
        acc[p].y = fmaf(wc, hv[p].y, acc[p].y);
        acc[p].z = fmaf(wc, hv[p].z, acc[p].z);
        acc[p].w = fmaf(wc, hv[p].w, acc[p].w);
      }
#pragma unroll
      for (int p = 0; p < NP; ++p) hv[p] = hn[p];
    }
  }

#pragma unroll
  for (int h = 0; h < H; ++h)
#pragma unroll
    for (int o = 8; o >= 1; o >>= 1) s_part[h] += __shfl_xor(s_part[h], o, 16);

#pragma unroll
  for (int p = 0; p < NP; ++p) {
    int c4 = (p * 16 + l) * 4;
    if (c4 < F) {
      float inv = 1.f / s_part[c4 / D];
      float4 o;
      o.x = acc[p].x * inv; o.y = acc[p].y * inv;
      o.z = acc[p].z * inv; o.w = acc[p].w * inv;
      if (RELU) {
        o.x = fmaxf(o.x, 0.f); o.y = fmaxf(o.y, 0.f);
        o.z = fmaxf(o.z, 0.f); o.w = fmaxf(o.w, 0.f);
      }
      *(float4*)(out + (size_t)d * F + c4) = o;
    }
  }
}

// ---------------------------------------------------------------------------
extern "C" void kernel_launch(void* const* d_in, const int* in_sizes, int n_in,
                              void* d_out, int out_size, void* d_ws, size_t ws_size,
                              hipStream_t stream) {
  const float* x   = (const float*)d_in[0];
  const int* src0  = (const int*)d_in[1];
  const int* dst0  = (const int*)d_in[2];
  const int* src1  = (const int*)d_in[3];
  const int* dst1  = (const int*)d_in[4];
  const int* src2  = (const int*)d_in[5];
  const int* dst2  = (const int*)d_in[6];
  const float* W0  = (const float*)d_in[7];
  const float* al0 = (const float*)d_in[8];
  const float* ar0 = (const float*)d_in[9];
  const float* W1  = (const float*)d_in[10];
  const float* al1 = (const float*)d_in[11];
  const float* ar1 = (const float*)d_in[12];
  const float* W2  = (const float*)d_in[13];
  const float* al2 = (const float*)d_in[14];
  const float* ar2 = (const float*)d_in[15];

  const int N0 = 200000, N1 = 100000, N2 = 50000, N3 = 25000;
  const int E0 = in_sizes[1], E1 = in_sizes[3], E2 = in_sizes[5];
  const int Fin = 256, F = 192, C = 40;

  // ---- workspace layout ----
  float* ws     = (float*)d_ws;
  float* h_buf  = ws;                         // 200000*192
  float* o_buf  = h_buf + (size_t)N0 * F;     // 100000*192
  float* el_buf = o_buf + (size_t)N1 * F;     // 200000*3
  float* er_buf = el_buf + (size_t)N0 * 3;    // 100000*3
  short* w0h    = (short*)(er_buf + (size_t)N1 * 3);
  short* w0l    = w0h + 192 * 256;
  short* w1h    = w0l + 192 * 256;
  short* w1l    = w1h + 192 * 192;
  short* w2h    = w1l + 192 * 192;
  short* w2l    = w2h + 40 * 192;
  int*   off0   = (int*)(w2l + 40 * 192);
  int*   off1   = off0 + (N1 + 1);
  int*   off2   = off1 + (N2 + 1);

  dim3 blk(256);

  // ---- pre-passes ----
  const int WTOT = 256 * 192 + 192 * 192 + 192 * 40;
  conv_w_all<<<dim3((WTOT + 255) / 256), blk, 0, stream>>>(W0, W1, W2, w0h, w0l, w1h, w1l, w2h, w2l);
  const int ETOT = E0 + E1 + E2;
  csr_all<<<dim3((ETOT + 255) / 256), blk, 0, stream>>>(dst0, dst1, dst2, off0, off1, off2,
                                                        E0, E1, E2, N1, N2, N3);

  // ---- Layer 0 ----
  gemm_fused<12, 3><<<dim3((N0 + 127) / 128), blk, 0, stream>>>(
      x, w0h, w0l, al0, ar0, h_buf, el_buf, er_buf, N0, F, Fin, N1);
  agg2_kernel<3, 64, true><<<dim3((N1 + 15) / 16), blk, 0, stream>>>(
      h_buf, el_buf, er_buf, src0, off0, o_buf, N1);

  // ---- Layer 1 ----
  gemm_fused<12, 3><<<dim3((N1 + 127) / 128), blk, 0, stream>>>(
      o_buf, w1h, w1l, al1, ar1, h_buf, el_buf, er_buf, N1, F, F, N2);
  agg2_kernel<3, 64, true><<<dim3((N2 + 15) / 16), blk, 0, stream>>>(
      h_buf, el_buf, er_buf, src1, off1, o_buf, N2);

  // ---- Layer 2 (N=40, H=1, no relu) ----
  gemm_fused<3, 1><<<dim3((N2 + 127) / 128), blk, 0, stream>>>(
      o_buf, w2h, w2l, al2, ar2, h_buf, el_buf, er_buf, N2, C, F, N3);
  agg2_kernel<1, 40, false><<<dim3((N3 + 15) / 16), blk, 0, stream>>>(
      h_buf, el_buf, er_buf, src2, off2, (float*)d_out, N3);
}